// Round 2
// baseline (1086.714 us; speedup 1.0000x reference)
//
#include <hip/hip_runtime.h>

// GlobalFilter (GFNet): out = irfft2(rfft2(x)·W, ortho) == per-channel 16x16
// circular convolution with k[:,:,c] = inverse transform of W (Hermitian-
// extended, Im dropped at self-conjugate cols v=0,8). ortho norms cancel.

constexpr int PP = 16;   // patch size
constexpr int NS = 256;  // PP*PP spatial
constexpr int CH = 768;  // channels
constexpr int NB = 128;  // batch
constexpr int CB = 16;   // channels per conv block
constexpr int XS = 20;   // padded LDS row stride (floats) for xs  (breaks 16-word stride conflicts)

// ---------------- Kernel A: build real conv kernel k[p*16+q][c] -------------
// Trig tables in LDS (dynamic indexing of register arrays -> scratch spill,
// which cost ~128us in round 1).
__global__ void gf_build_k(const float* __restrict__ w, float* __restrict__ kbuf) {
    __shared__ float ct[16], st[16];
    if (threadIdx.x < 16) {
        const float ang = 6.28318530717958647692f * (float)threadIdx.x * (1.0f / 16.0f);
        ct[threadIdx.x] = cosf(ang);
        st[threadIdx.x] = sinf(ang);
    }
    __syncthreads();

    const int pq = blockIdx.x;                              // 0..255
    const int c  = blockIdx.y * blockDim.x + threadIdx.x;   // 0..767
    const int p = pq >> 4, q = pq & 15;

    float acc = 0.0f;
#pragma unroll
    for (int u = 0; u < 16; ++u) {
#pragma unroll
        for (int v = 0; v <= 8; ++v) {
            const float cv = (v == 0 || v == 8) ? 1.0f : 2.0f;
            const int t = (u * p + v * q) & 15;
            const float* wp = w + 2 * ((size_t)((u * 9 + v) * CH) + c);
            acc += cv * (wp[0] * ct[t] - wp[1] * st[t]);
        }
    }
    kbuf[pq * CH + c] = acc * (1.0f / 256.0f);
}

// ---------------- Kernel B: depthwise 16x16 circular conv -------------------
// block = (16 channels, one batch b), 128 threads = 4 ch-groups x 16 n x 2 m-halves.
// Both x-tile and k-tile live in LDS (k from global stalled round 1: VALUBusy 52%).
__global__ __launch_bounds__(128, 2) void gf_conv(const float* __restrict__ x,
                                                  const float* __restrict__ kbuf,
                                                  float* __restrict__ out) {
    __shared__ __align__(16) float xs[NS][XS];  // [r*16 + j][ch]  20 KB
    __shared__ __align__(16) float ks[NS][CB];  // [p*16 + q][ch]  16 KB

    const int b   = blockIdx.y;
    const int c0  = blockIdx.x * CB;
    const int tid = threadIdx.x;

    // ---- stage x[b, :, c0:c0+16] and k[:, c0:c0+16] (b128 both sides) ----
    {
        const float* xb = x + (size_t)b * NS * CH + c0;
        const float* kb = kbuf + c0;
#pragma unroll
        for (int i = 0; i < 8; ++i) {
            const int T  = i * 128 + tid;   // 0..1023
            const int s  = T >> 2;          // spatial / pq index 0..255
            const int g4 = (T & 3) << 2;    // ch offset 0,4,8,12
            *(float4*)&xs[s][g4] = *(const float4*)(xb + (size_t)s * CH + g4);
            *(float4*)&ks[s][g4] = *(const float4*)(kb + (size_t)s * CH + g4);
        }
    }
    __syncthreads();

    const int ch = (tid & 3) << 2;   // channel offset within tile: 0,4,8,12
    const int n  = (tid >> 2) & 15;  // output column
    const int mb = (tid >> 6) << 3;  // m base: 0 or 8

    float4 acc[8];
#pragma unroll
    for (int m = 0; m < 8; ++m) acc[m] = make_float4(0.f, 0.f, 0.f, 0.f);

#pragma unroll 1
    for (int q = 0; q < 16; ++q) {
        const int j = (n - q) & 15;  // x column (lane-varying; XS=20 kills conflicts)

        float4 xv[16];
#pragma unroll
        for (int r = 0; r < 16; ++r)
            xv[r] = *(const float4*)&xs[(r << 4) + j][ch];

#pragma unroll
        for (int p = 0; p < 16; ++p) {
            const float4 kv = *(const float4*)&ks[(p << 4) + q][ch];  // wave-uniform -> broadcast
#pragma unroll
            for (int m = 0; m < 8; ++m) {
                const float4 xx = xv[(mb + m - p) & 15];
                acc[m].x = fmaf(kv.x, xx.x, acc[m].x);
                acc[m].y = fmaf(kv.y, xx.y, acc[m].y);
                acc[m].z = fmaf(kv.z, xx.z, acc[m].z);
                acc[m].w = fmaf(kv.w, xx.w, acc[m].w);
            }
        }
    }

    float* ob = out + (size_t)b * NS * CH + c0 + ch;
#pragma unroll
    for (int m = 0; m < 8; ++m)
        *(float4*)(ob + (size_t)(((mb + m) << 4) + n) * CH) = acc[m];
}

// ---------------------------------------------------------------------------
extern "C" void kernel_launch(void* const* d_in, const int* in_sizes, int n_in,
                              void* d_out, int out_size, void* d_ws, size_t ws_size,
                              hipStream_t stream) {
    const float* x = (const float*)d_in[0];        // [128, 256, 768] fp32
    const float* w = (const float*)d_in[1];        // [16, 9, 768, 2] fp32
    float* out  = (float*)d_out;                   // [128, 256, 768] fp32
    float* kbuf = (float*)d_ws;                    // 256*768 fp32 = 768 KB

    gf_build_k<<<dim3(256, 3), 256, 0, stream>>>(w, kbuf);
    gf_conv<<<dim3(CH / CB, NB), 128, 0, stream>>>(x, kbuf, out);
}

// Round 3
// 384.590 us; speedup vs baseline: 2.8256x; 2.8256x over previous
//
#include <hip/hip_runtime.h>

// GlobalFilter (GFNet): out = irfft2(rfft2(x)·W, ortho) == per-channel 16x16
// circular convolution with k[:,:,c] = inverse transform of W (Hermitian-
// extended, Im dropped at self-conjugate cols v=0,8). ortho norms cancel.
//
// R2 lesson: NEVER dynamically index a register array (xv[runtime] -> scratch,
// 2.5 GB scratch traffic). NEVER lane-vary the LDS column of float4 reads
// (all starts are mult-of-4 -> max 8 bank residues -> 8-way conflicts).
// R1 structure (q-stagger -> wave-uniform j -> broadcast xv, all indices
// static) is the correct skeleton; only kv global-load latency needed fixing.

constexpr int PP = 16;   // patch size
constexpr int NS = 256;  // PP*PP spatial
constexpr int CH = 768;  // channels
constexpr int NB = 128;  // batch

// ---------------- Kernel A: build real conv kernel k[p*16+q][c] -------------
// Trig tables in LDS (dynamic reg-array indexing spills to scratch: R1 cost
// ~128us). u-loop unroll 1 keeps live loads to 18 (full unroll = 288 live
// loads -> register exhaustion -> scratch: suspected R2 cost ~100us).
__global__ void gf_build_k(const float* __restrict__ w, float* __restrict__ kbuf) {
    __shared__ float ct[16], st[16];
    if (threadIdx.x < 16) {
        const float ang = 6.28318530717958647692f * (float)threadIdx.x * (1.0f / 16.0f);
        ct[threadIdx.x] = cosf(ang);
        st[threadIdx.x] = sinf(ang);
    }
    __syncthreads();

    const int pq = blockIdx.x;                              // 0..255
    const int c  = blockIdx.y * blockDim.x + threadIdx.x;   // 0..767
    const int p = pq >> 4, q = pq & 15;

    float acc = 0.0f;
#pragma unroll 1
    for (int u = 0; u < 16; ++u) {
        const float* wu = w + (size_t)(u * 9) * 2 * CH + 2 * c;
#pragma unroll
        for (int v = 0; v < 9; ++v) {
            const float cv = (v == 0 || v == 8) ? 1.0f : 2.0f;
            const int t = (u * p + v * q) & 15;  // lane-uniform -> LDS broadcast
            const float wr = wu[(size_t)v * 2 * CH];
            const float wi = wu[(size_t)v * 2 * CH + 1];
            acc += cv * (wr * ct[t] - wi * st[t]);
        }
    }
    kbuf[pq * CH + c] = acc * (1.0f / 256.0f);
}

// ---------------- Kernel B: depthwise 16x16 circular conv -------------------
// block = (32 channels, one batch b), 128 threads.
// thread: 4 channels (float4) x 1 n-column x all 16 m rows (64 acc VGPRs).
// q staggered by n -> xv LDS reads are wave-uniform (broadcast, 0 conflicts).
// kv from global (L2-hot) with a manual 4-deep rolling prefetch window:
// distance 4 p-steps = ~256 cy of FMAs > L2 hit latency (~200 cy).
__global__ __launch_bounds__(128, 3) void gf_conv(const float* __restrict__ x,
                                                  const float* __restrict__ kbuf,
                                                  float* __restrict__ out) {
    __shared__ __align__(16) float xs[NS][32];
    const int b   = blockIdx.y;
    const int c0  = blockIdx.x * 32;
    const int tid = threadIdx.x;

    // ---- stage x[b, :, c0:c0+32] into LDS (b128 loads/stores) ----
    {
        const int ch4 = (tid & 7) << 2;
        const int sr  = tid >> 3;  // 0..15
        const float* xb = x + (size_t)b * NS * CH + c0;
#pragma unroll
        for (int i = 0; i < 16; ++i) {
            const int s = (i << 4) + sr;
            *(float4*)&xs[s][ch4] = *(const float4*)(xb + (size_t)s * CH + ch4);
        }
    }
    __syncthreads();

    const int ch = (tid & 7) << 2;  // channel offset within tile (float4 group)
    const int n  = tid >> 3;        // output column 0..15

    float4 acc[16];
#pragma unroll
    for (int m = 0; m < 16; ++m) acc[m] = make_float4(0.f, 0.f, 0.f, 0.f);

    const float* kb = kbuf + c0 + ch;

#pragma unroll 1
    for (int qq = 0; qq < 16; ++qq) {
        const int q = (qq + n) & 15;
        const int j = (n - q) & 15;  // == (-qq)&15, lane-uniform -> broadcast reads

        const float* kq = kb + (size_t)q * CH;  // k[(p*16+q)*CH + c]; p stride 16*CH

        float4 xv[16];
#pragma unroll
        for (int r = 0; r < 16; ++r)
            xv[r] = *(const float4*)&xs[(r << 4) + j][ch];

        float4 kw[4];
#pragma unroll
        for (int p = 0; p < 4; ++p)
            kw[p] = *(const float4*)(kq + (size_t)p * 16 * CH);

#pragma unroll
        for (int p = 0; p < 16; ++p) {
            const float4 kv = kw[p & 3];          // p&3 static after unroll
            if (p + 4 < 16)
                kw[p & 3] = *(const float4*)(kq + (size_t)(p + 4) * 16 * CH);
#pragma unroll
            for (int m = 0; m < 16; ++m) {
                const float4 xx = xv[(m - p) & 15];  // static after unroll
                acc[m].x = fmaf(kv.x, xx.x, acc[m].x);
                acc[m].y = fmaf(kv.y, xx.y, acc[m].y);
                acc[m].z = fmaf(kv.z, xx.z, acc[m].z);
                acc[m].w = fmaf(kv.w, xx.w, acc[m].w);
            }
        }
    }

    float* ob = out + (size_t)b * NS * CH + c0 + ch;
#pragma unroll
    for (int m = 0; m < 16; ++m)
        *(float4*)(ob + (size_t)((m << 4) + n) * CH) = acc[m];
}

// ---------------------------------------------------------------------------
extern "C" void kernel_launch(void* const* d_in, const int* in_sizes, int n_in,
                              void* d_out, int out_size, void* d_ws, size_t ws_size,
                              hipStream_t stream) {
    const float* x = (const float*)d_in[0];        // [128, 256, 768] fp32
    const float* w = (const float*)d_in[1];        // [16, 9, 768, 2] fp32
    float* out  = (float*)d_out;                   // [128, 256, 768] fp32
    float* kbuf = (float*)d_ws;                    // 256*768 fp32 = 768 KB

    gf_build_k<<<dim3(256, 3), 256, 0, stream>>>(w, kbuf);
    gf_conv<<<dim3(CH / 32, NB), 128, 0, stream>>>(x, kbuf, out);
}

// Round 4
// 300.318 us; speedup vs baseline: 3.6185x; 1.2806x over previous
//
#include <hip/hip_runtime.h>

// GlobalFilter (GFNet): out = irfft2(rfft2(x)·W, ortho) == per-channel 16x16
// circular convolution with k[:,:,c] = inverse transform of W (Hermitian-
// extended, Im dropped at self-conjugate cols v=0,8). ortho norms cancel.
//
// Lessons:
//  R1: k from global -> exposed L2 latency, VALUBusy 52%.
//  R2: lane-varying LDS x-column -> bank conflicts; dynamic reg-array index
//      -> scratch (2.5 GB). NEVER index a register array with a runtime value.
//  R3: prefetch window + conditional inside unrolled loop -> spill (WRITE
//      165 MB vs 98 MB out). NEVER put conditionals in hot unrolled loops.
//  Total-vs-conv gap is ~110 us across 3 different build_k variants ->
//  mostly fixed harness overhead; gf_conv is the only big controllable term.
//
// R4: both tiles in LDS (64 KB, 2 blocks/CU). q-stagger keeps xv reads
// wave-uniform (broadcast). kv reads are distinct-address b128 = full LDS BW.
// Inner loops over (d = m-p, p): only kv[16]+acc[16]+xx live, all indices
// static, no conditionals. Loop body has zero global loads.

constexpr int PP = 16;   // patch size
constexpr int NS = 256;  // PP*PP spatial
constexpr int CH = 768;  // channels
constexpr int NB = 128;  // batch

// ---------------- Kernel A: build real conv kernel k[p*16+q][c] -------------
__global__ void gf_build_k(const float* __restrict__ w, float* __restrict__ kbuf) {
    __shared__ float ct[16], st[16];
    if (threadIdx.x < 16) {
        const float ang = 6.28318530717958647692f * (float)threadIdx.x * (1.0f / 16.0f);
        ct[threadIdx.x] = cosf(ang);
        st[threadIdx.x] = sinf(ang);
    }
    __syncthreads();

    const int pq = blockIdx.x;                              // 0..255
    const int c  = blockIdx.y * blockDim.x + threadIdx.x;   // 0..767
    const int p = pq >> 4, q = pq & 15;

    float acc = 0.0f;
#pragma unroll 1
    for (int u = 0; u < 16; ++u) {
        const float* wu = w + (size_t)(u * 9) * 2 * CH + 2 * c;
#pragma unroll
        for (int v = 0; v < 9; ++v) {
            const float cv = (v == 0 || v == 8) ? 1.0f : 2.0f;
            const int t = (u * p + v * q) & 15;  // lane-uniform -> LDS broadcast
            const float wr = wu[(size_t)v * 2 * CH];
            const float wi = wu[(size_t)v * 2 * CH + 1];
            acc += cv * (wr * ct[t] - wi * st[t]);
        }
    }
    kbuf[pq * CH + c] = acc * (1.0f / 256.0f);
}

// ---------------- Kernel B: depthwise 16x16 circular conv -------------------
// block = (32 channels, one batch b), 128 threads.
// thread: 4 channels (float4) x 1 n-column x all 16 m rows.
__global__ __launch_bounds__(128, 2) void gf_conv(const float* __restrict__ x,
                                                  const float* __restrict__ kbuf,
                                                  float* __restrict__ out) {
    __shared__ __align__(16) float xs[NS][32];  // x[b, m*16+n, c-tile]   32 KB
    __shared__ __align__(16) float ks[NS][32];  // k[p*16+q, c-tile]      32 KB

    const int b   = blockIdx.y;
    const int c0  = blockIdx.x * 32;
    const int tid = threadIdx.x;

    // ---- stage x-tile and k-tile (b128 both sides, no conflicts: R1 pattern)
    {
        const int ch4 = (tid & 7) << 2;
        const int sr  = tid >> 3;  // 0..15
        const float* xb = x + (size_t)b * NS * CH + c0;
        const float* kb = kbuf + c0;
#pragma unroll
        for (int i = 0; i < 16; ++i) {
            const int s = (i << 4) + sr;
            *(float4*)&xs[s][ch4] = *(const float4*)(xb + (size_t)s * CH + ch4);
            *(float4*)&ks[s][ch4] = *(const float4*)(kb + (size_t)s * CH + ch4);
        }
    }
    __syncthreads();

    const int ch = (tid & 7) << 2;  // channel offset within tile (float4 group)
    const int n  = tid >> 3;        // output column 0..15

    float4 acc[16];
#pragma unroll
    for (int m = 0; m < 16; ++m) acc[m] = make_float4(0.f, 0.f, 0.f, 0.f);

#pragma unroll 1
    for (int qq = 0; qq < 16; ++qq) {
        const int q = (qq + n) & 15;  // lane-varying k column
        const int j = (n - q) & 15;   // == (-qq)&15: lane-UNIFORM x column -> broadcast

        // kv[16]: 16 distinct-address b128 LDS reads (spread across all 8
        // bank-quads via ch -> full LDS BW; counted as "conflicts" but BW-optimal)
        float4 kv[16];
#pragma unroll
        for (int p = 0; p < 16; ++p)
            kv[p] = *(const float4*)&ks[(p << 4) | q][ch];

        // d = (m - p) & 15: one broadcast x row per d, 16 static-indexed FMAs
#pragma unroll
        for (int d = 0; d < 16; ++d) {
            const float4 xx = *(const float4*)&xs[(d << 4) + j][ch];
#pragma unroll
            for (int p = 0; p < 16; ++p) {
                const int m = (p + d) & 15;  // compile-time
                acc[m].x = fmaf(kv[p].x, xx.x, acc[m].x);
                acc[m].y = fmaf(kv[p].y, xx.y, acc[m].y);
                acc[m].z = fmaf(kv[p].z, xx.z, acc[m].z);
                acc[m].w = fmaf(kv[p].w, xx.w, acc[m].w);
            }
        }
    }

    float* ob = out + (size_t)b * NS * CH + c0 + ch;
#pragma unroll
    for (int m = 0; m < 16; ++m)
        *(float4*)(ob + (size_t)((m << 4) + n) * CH) = acc[m];
}

// ---------------------------------------------------------------------------
extern "C" void kernel_launch(void* const* d_in, const int* in_sizes, int n_in,
                              void* d_out, int out_size, void* d_ws, size_t ws_size,
                              hipStream_t stream) {
    const float* x = (const float*)d_in[0];        // [128, 256, 768] fp32
    const float* w = (const float*)d_in[1];        // [16, 9, 768, 2] fp32
    float* out  = (float*)d_out;                   // [128, 256, 768] fp32
    float* kbuf = (float*)d_ws;                    // 256*768 fp32 = 768 KB

    gf_build_k<<<dim3(256, 3), 256, 0, stream>>>(w, kbuf);
    gf_conv<<<dim3(CH / 32, NB), 128, 0, stream>>>(x, kbuf, out);
}